// Round 16
// baseline (135.104 us; speedup 1.0000x reference)
//
#include <hip/hip_runtime.h>
#include <cmath>

#define BB  4
#define VV  4096
#define KK  40
#define FIN 64

typedef float v2f __attribute__((ext_vector_type(2)));

// ---------------------------------------------------------------------------
// Kernel A: 16 rows/block (4 waves x 4 rows). feats GEMM uses the
// 4-rows-per-LDS-instr layout: lane = rgrp*16 + colg; each ds_read_b128
// returns k4-chunks of 4 DIFFERENT rows (64B payload vs 16B broadcast).
// Row stride 68 (== 4 mod 32) makes the 4 rows hit distinct bank quads.
// x staged per-wave (no barrier needed); accumulation order = k ascending,
// bias added last — bit-identical to the previous prep.
// ---------------------------------------------------------------------------
__global__ __launch_bounds__(256) void prep_kernel(
    const float* __restrict__ x, const float* __restrict__ Wf,
    const float* __restrict__ bf, const float* __restrict__ Ws,
    const float* __restrict__ bs,
    float* __restrict__ coords, float* __restrict__ feats)
{
    int tid  = threadIdx.x;
    int lane = tid & 63;
    int w    = tid >> 6;
    int row0 = blockIdx.x * 16 + w * 4;            // this wave's 4 rows

    __shared__ __align__(16) float sx[16 * 68];    // stride 68 = 4 mod 32

    #pragma unroll
    for (int i = 0; i < 4; ++i)                    // stage own rows, coalesced
        sx[(w * 4 + i) * 68 + lane] = x[(size_t)(row0 + i) * 64 + lane];
    // same-wave LDS write->read: compiler inserts waitcnt, no barrier

    int rgrp = lane >> 4;                          // row within quad
    int colg = lane & 15;                          // float4 column group
    const float4* Wf4 = (const float4*)Wf;
    float4 acc = make_float4(0.f, 0.f, 0.f, 0.f);
    #pragma unroll 4
    for (int k4 = 0; k4 < 16; ++k4) {
        float4 u  = *(const float4*)&sx[(w * 4 + rgrp) * 68 + k4 * 4];
        float4 w0 = Wf4[(k4 * 4 + 0) * 16 + colg];
        float4 w1 = Wf4[(k4 * 4 + 1) * 16 + colg];
        float4 w2 = Wf4[(k4 * 4 + 2) * 16 + colg];
        float4 w3 = Wf4[(k4 * 4 + 3) * 16 + colg];
        acc.x = fmaf(u.x, w0.x, acc.x); acc.y = fmaf(u.x, w0.y, acc.y);
        acc.z = fmaf(u.x, w0.z, acc.z); acc.w = fmaf(u.x, w0.w, acc.w);
        acc.x = fmaf(u.y, w1.x, acc.x); acc.y = fmaf(u.y, w1.y, acc.y);
        acc.z = fmaf(u.y, w1.z, acc.z); acc.w = fmaf(u.y, w1.w, acc.w);
        acc.x = fmaf(u.z, w2.x, acc.x); acc.y = fmaf(u.z, w2.y, acc.y);
        acc.z = fmaf(u.z, w2.z, acc.z); acc.w = fmaf(u.z, w2.w, acc.w);
        acc.x = fmaf(u.w, w3.x, acc.x); acc.y = fmaf(u.w, w3.y, acc.y);
        acc.z = fmaf(u.w, w3.z, acc.z); acc.w = fmaf(u.w, w3.w, acc.w);
    }
    float4 bf4 = ((const float4*)bf)[colg];
    acc.x += bf4.x; acc.y += bf4.y; acc.z += bf4.z; acc.w += bf4.w;
    *(float4*)&feats[(size_t)(row0 + rgrp) * 64 + colg * 4] = acc;

    // coords for the same 4 rows (per-lane global reads, unchanged)
    int r  = lane >> 4;                            // 0..3 row
    int s  = (lane >> 2) & 3;                      // 0..3 coord dim
    int kc = lane & 3;                             // 0..3 k-chunk
    const float* xrr = x + (size_t)(row0 + r) * FIN + kc * 16;
    const float* wsr = Ws + kc * 16 * 4 + s;
    float c = 0.f;
    #pragma unroll
    for (int k = 0; k < 16; ++k)
        c = fmaf(xrr[k], wsr[k * 4], c);
    c += __shfl_xor(c, 1, 64);                     // reduce over kc
    c += __shfl_xor(c, 2, 64);
    float val = c + bs[s];
    if ((lane & 3) == 0) coords[(size_t)(row0 + r) * 4 + s] = val;
}

// ---------------------------------------------------------------------------
// Spill-proof helpers (rounds 9/10 lesson: no runtime-indexed locals).
// ---------------------------------------------------------------------------
__device__ __forceinline__ unsigned umed3(unsigned a, unsigned b, unsigned c)
{
    unsigned d;
    asm("v_med3_u32 %0, %1, %2, %3" : "=v"(d) : "v"(a), "v"(b), "v"(c));
    return d;
}

__device__ __forceinline__ int cnt_lt4(unsigned m0, unsigned m1,
                                       unsigned m2, unsigned m3,
                                       unsigned cand)
{
    return (int)__popcll(__ballot(m0 < cand))
         + (int)__popcll(__ballot(m1 < cand))
         + (int)__popcll(__ballot(m2 < cand))
         + (int)__popcll(__ballot(m3 < cand));
}

__device__ __forceinline__ unsigned select_thresh(unsigned m0, unsigned m1,
                                                  unsigned m2, unsigned m3)
{
    unsigned M = 0u;
    #pragma unroll
    for (int bit = 30; bit >= 12; --bit) {
        unsigned cand = M | (1u << bit);
        if (cnt_lt4(m0, m1, m2, m3, cand) <= 39) M = cand;
    }
    unsigned Msel = M | 0xFFFu;
    if (cnt_lt4(m0, m1, m2, m3, M + 4096u) != 40) {
        #pragma unroll
        for (int bit = 11; bit >= 0; --bit) {
            unsigned cand = M | (1u << bit);
            if (cnt_lt4(m0, m1, m2, m3, cand) <= 39) M = cand;
        }
        Msel = M;
    }
    return Msel;
}

__device__ __forceinline__ void compact4(unsigned m0, unsigned m1,
                                         unsigned m2, unsigned m3,
                                         unsigned Msel, uint2* dst)
{
    unsigned mn = m0;
    #pragma unroll
    for (int off = 32; off >= 1; off >>= 1) {
        unsigned o = __shfl_xor(mn, off, 64);
        mn = o < mn ? o : mn;
    }
    int base = 0;
    unsigned kk = m0;
    #pragma unroll
    for (int i = 0; i < 4; ++i) {
        bool pred = (kk <= Msel) && (kk != mn);
        unsigned long long mask = __ballot(pred);
        unsigned pos = (unsigned)base +
            __builtin_amdgcn_mbcnt_hi((unsigned)(mask >> 32),
                __builtin_amdgcn_mbcnt_lo((unsigned)mask, 0u));
        if (pred) {
            float d2a = __uint_as_float(kk & 0xFFFFF000u);
            float w   = __expf(-10.f * d2a);
            dst[pos] = make_uint2((kk & 4095u) << 8, __float_as_uint(w));
        }
        base += (int)__popcll(mask);
        kk = (i == 0) ? m1 : (i == 1) ? m2 : m3;   // static rotation
    }
}

// ---------------------------------------------------------------------------
// Kernel B (lite): unchanged from rounds 14/15 (42.6 us, spill-free).
// ---------------------------------------------------------------------------
__global__ __launch_bounds__(128) void gravnet_kernel(
    const float* __restrict__ coords, const float* __restrict__ feats,
    float* __restrict__ mxp, float* __restrict__ mnp)
{
    int lane = threadIdx.x & 63;
    int w    = threadIdx.x >> 6;              // wave 0..1
    int qb   = blockIdx.x * 4;                // quad's first global query
    int b    = qb >> 12;
    int v0   = qb & (VV - 1);

    __shared__ __align__(16) char smem[8192];
    uint4* s_mrg = (uint4*)smem;                       // [2][4][64] phase 1
    uint2* s_nb  = (uint2*)smem;                       // [4][KK]    phase 2

    const float4* cb = (const float4*)(coords + (size_t)b * VV * 4);

    float4 cq0 = cb[v0],     cq1 = cb[v0 + 1];
    float4 cq2 = cb[v0 + 2], cq3 = cb[v0 + 3];
    float sv0 = fmaf(cq0.w, cq0.w, fmaf(cq0.z, cq0.z,
                fmaf(cq0.y, cq0.y, cq0.x * cq0.x)));
    float sv1 = fmaf(cq1.w, cq1.w, fmaf(cq1.z, cq1.z,
                fmaf(cq1.y, cq1.y, cq1.x * cq1.x)));
    float sv2 = fmaf(cq2.w, cq2.w, fmaf(cq2.z, cq2.z,
                fmaf(cq2.y, cq2.y, cq2.x * cq2.x)));
    float sv3 = fmaf(cq3.w, cq3.w, fmaf(cq3.z, cq3.z,
                fmaf(cq3.y, cq3.y, cq3.x * cq3.x)));
    v2f nxA = (v2f){-2.f * cq0.x, -2.f * cq1.x};
    v2f nyA = (v2f){-2.f * cq0.y, -2.f * cq1.y};
    v2f nzA = (v2f){-2.f * cq0.z, -2.f * cq1.z};
    v2f nwA = (v2f){-2.f * cq0.w, -2.f * cq1.w};
    v2f hsA = (v2f){sv0, sv1};
    v2f nxB = (v2f){-2.f * cq2.x, -2.f * cq3.x};
    v2f nyB = (v2f){-2.f * cq2.y, -2.f * cq3.y};
    v2f nzB = (v2f){-2.f * cq2.z, -2.f * cq3.z};
    v2f nwB = (v2f){-2.f * cq2.w, -2.f * cq3.w};
    v2f hsB = (v2f){sv2, sv3};
    v2f zero = (v2f){0.f, 0.f};

    unsigned k00 = ~0u, k01 = ~0u, k02 = ~0u, k03 = ~0u;
    unsigned k10 = ~0u, k11 = ~0u, k12 = ~0u, k13 = ~0u;
    unsigned k20 = ~0u, k21 = ~0u, k22 = ~0u, k23 = ~0u;
    unsigned k30 = ~0u, k31 = ~0u, k32 = ~0u, k33 = ~0u;

    int i0 = w * 32;                           // this wave's candidate half
    #pragma unroll 4
    for (int i = i0; i < i0 + 32; ++i) {
        int u = i * 64 + lane;
        float4 cu = cb[u];                     // the only VMEM stream
        float squ = fmaf(cu.w, cu.w, fmaf(cu.z, cu.z,
                    fmaf(cu.y, cu.y, cu.x * cu.x)));
        v2f accA = hsA + (v2f){squ, squ};
        accA = __builtin_elementwise_fma(nxA, (v2f){cu.x, cu.x}, accA);
        accA = __builtin_elementwise_fma(nyA, (v2f){cu.y, cu.y}, accA);
        accA = __builtin_elementwise_fma(nzA, (v2f){cu.z, cu.z}, accA);
        accA = __builtin_elementwise_fma(nwA, (v2f){cu.w, cu.w}, accA);
        v2f accB = hsB + (v2f){squ, squ};
        accB = __builtin_elementwise_fma(nxB, (v2f){cu.x, cu.x}, accB);
        accB = __builtin_elementwise_fma(nyB, (v2f){cu.y, cu.y}, accB);
        accB = __builtin_elementwise_fma(nzB, (v2f){cu.z, cu.z}, accB);
        accB = __builtin_elementwise_fma(nwB, (v2f){cu.w, cu.w}, accB);
        accA = __builtin_elementwise_max(accA, zero);   // v_pk_max_f32
        accB = __builtin_elementwise_max(accB, zero);   // keys non-negative

        {
            unsigned k = (__float_as_uint(accA.x) & 0xFFFFF000u) | (unsigned)u;
            unsigned n1 = umed3(k00, k01, k);
            unsigned n2 = umed3(k01, k02, k);
            unsigned n3 = umed3(k02, k03, k);
            k00 = min(k00, k); k01 = n1; k02 = n2; k03 = n3;
        }
        {
            unsigned k = (__float_as_uint(accA.y) & 0xFFFFF000u) | (unsigned)u;
            unsigned n1 = umed3(k10, k11, k);
            unsigned n2 = umed3(k11, k12, k);
            unsigned n3 = umed3(k12, k13, k);
            k10 = min(k10, k); k11 = n1; k12 = n2; k13 = n3;
        }
        {
            unsigned k = (__float_as_uint(accB.x) & 0xFFFFF000u) | (unsigned)u;
            unsigned n1 = umed3(k20, k21, k);
            unsigned n2 = umed3(k21, k22, k);
            unsigned n3 = umed3(k22, k23, k);
            k20 = min(k20, k); k21 = n1; k22 = n2; k23 = n3;
        }
        {
            unsigned k = (__float_as_uint(accB.y) & 0xFFFFF000u) | (unsigned)u;
            unsigned n1 = umed3(k30, k31, k);
            unsigned n2 = umed3(k31, k32, k);
            unsigned n3 = umed3(k32, k33, k);
            k30 = min(k30, k); k31 = n1; k32 = n2; k33 = n3;
        }
    }

    s_mrg[(w * 4 + 0) * 64 + lane] = make_uint4(k00, k01, k02, k03);
    s_mrg[(w * 4 + 1) * 64 + lane] = make_uint4(k10, k11, k12, k13);
    s_mrg[(w * 4 + 2) * 64 + lane] = make_uint4(k20, k21, k22, k23);
    s_mrg[(w * 4 + 3) * 64 + lane] = make_uint4(k30, k31, k32, k33);
    __syncthreads();                           // pair-local barrier

    int p   = w ^ 1;
    int lq0 = w * 2;                           // local query within quad
    uint4 pb0 = s_mrg[(p * 4 + lq0)     * 64 + lane];
    uint4 pb1 = s_mrg[(p * 4 + lq0 + 1) * 64 + lane];
    unsigned oa0 = w ? k20 : k00, oa1 = w ? k21 : k01;
    unsigned oa2 = w ? k22 : k02, oa3 = w ? k23 : k03;
    unsigned ob0 = w ? k30 : k10, ob1 = w ? k31 : k11;
    unsigned ob2 = w ? k32 : k12, ob3 = w ? k33 : k13;
    __syncthreads();                           // before s_nb reuse

    unsigned d0 = min(oa0, pb0.w), d1 = min(oa1, pb0.z);
    unsigned d2 = min(oa2, pb0.y), d3 = min(oa3, pb0.x);
    unsigned A0 = min(d0, d3), A3 = max(d0, d3);      // A0 = lane min
    unsigned e0 = min(ob0, pb1.w), e1 = min(ob1, pb1.z);
    unsigned e2 = min(ob2, pb1.y), e3 = min(ob3, pb1.x);
    unsigned B0 = min(e0, e3), B3 = max(e0, e3);

    int s0 = w * 2, s1 = w * 2 + 1;            // LDS slots
    compact4(A0, d1, d2, A3, select_thresh(A0, d1, d2, A3), &s_nb[s0 * KK]);
    compact4(B0, e1, e2, B3, select_thresh(B0, e1, e2, B3), &s_nb[s1 * KK]);

    const float* fb  = feats + (size_t)b * VV * 64;
    const char*  fbl = (const char*)(fb + lane);
    float vmax0 = -INFINITY, vsum0 = 0.f, vmax1 = -INFINITY, vsum1 = 0.f;
    #pragma unroll 6
    for (int j = 0; j < KK - 1; ++j) {
        uint2 n0 = s_nb[s0 * KK + j];          // ds_read_b64 x2
        uint2 n1 = s_nb[s1 * KK + j];
        float f0 = *(const float*)(fbl + n0.x);
        float f1 = *(const float*)(fbl + n1.x);
        float g0 = __uint_as_float(n0.y) * f0;
        float g1 = __uint_as_float(n1.y) * f1;
        vmax0 = fmaxf(vmax0, g0); vsum0 += g0;
        vmax1 = fmaxf(vmax1, g1); vsum1 += g1;
    }

    int q0g = qb + lq0, q1g = qb + lq0 + 1;
    mxp[(size_t)q0g * 64 + lane] = vmax0;
    mnp[(size_t)q0g * 64 + lane] = vsum0 * (1.0f / 39.0f);
    mxp[(size_t)q1g * 64 + lane] = vmax1;
    mnp[(size_t)q1g * 64 + lane] = vsum1 * (1.0f / 39.0f);
}

// ---------------------------------------------------------------------------
// Kernel C: out = tanh([x | mx | mn] @ Wo + bo).
// Round-15 lesson: wave-uniform ds_read_b128 broadcasts carry 16B payload
// -> 786K LDS instrs -> ~15 us pipe-bound. New layout: lane = rgrp*16+colg;
// one ds_read_b128 serves 4 DIFFERENT rows (64B payload). Row stride 196
// (== 4 mod 32) puts the 4 rows on distinct bank quads (conflict-free).
// Per wave: 8 rows as 2 passes; per k4: 4 Wo b128 (quarter-coalesced,
// L1-shared) + 2 LDS reads + 32 fma. Accumulation: bias first, k ascending
// x->mx->mn -- bit-identical to previous epilogue. mx aliases out: rows are
// fully staged + barriered before this block writes them.
// ---------------------------------------------------------------------------
__global__ __launch_bounds__(256) void out_gemm(
    const float* __restrict__ x, const float* __restrict__ mx,
    const float* __restrict__ mn, const float* __restrict__ Wo,
    const float* __restrict__ bo, float* __restrict__ out)
{
    int tid  = threadIdx.x;
    int lane = tid & 63;
    int w    = tid >> 6;                       // wave 0..3
    int r0   = blockIdx.x * 32;                // 32 rows per block

    __shared__ __align__(16) float sU[32 * 196];   // stride 196 = 4 mod 32

    {   // cooperative staging, coalesced
        const float* sx = x  + (size_t)r0 * 64;
        const float* sm = mx + (size_t)r0 * 64;
        const float* sn = mn + (size_t)r0 * 64;
        #pragma unroll
        for (int it = 0; it < 8; ++it) {
            int idx = it * 256 + tid;          // r = idx>>6, c = idx&63
            int r = idx >> 6, c = idx & 63;
            float vx = sx[idx];
            float vm = sm[idx];
            float vn = sn[idx];
            sU[r * 196 + c]       = vx;
            sU[r * 196 + 64 + c]  = vm;
            sU[r * 196 + 128 + c] = vn;
        }
    }
    __syncthreads();

    int rgrp = lane >> 4;                      // row within quad
    int colg = lane & 15;                      // float4 column group
    const float4* Wo4 = (const float4*)Wo;
    float4 bo4 = ((const float4*)bo)[colg];
    float4 accA = bo4, accB = bo4;             // bias first (as before)
    int rowA = (w * 8 + rgrp) * 196;           // pass 0 row base
    int rowB = (w * 8 + 4 + rgrp) * 196;       // pass 1 row base

    #pragma unroll 4
    for (int k4 = 0; k4 < 48; ++k4) {
        float4 w0 = Wo4[(k4 * 4 + 0) * 16 + colg];
        float4 w1 = Wo4[(k4 * 4 + 1) * 16 + colg];
        float4 w2 = Wo4[(k4 * 4 + 2) * 16 + colg];
        float4 w3 = Wo4[(k4 * 4 + 3) * 16 + colg];
        float4 uA = *(const float4*)&sU[rowA + k4 * 4];  // 4-row payload
        float4 uB = *(const float4*)&sU[rowB + k4 * 4];
        accA.x = fmaf(uA.x, w0.x, accA.x); accA.y = fmaf(uA.x, w0.y, accA.y);
        accA.z = fmaf(uA.x, w0.z, accA.z); accA.w = fmaf(uA.x, w0.w, accA.w);
        accA.x = fmaf(uA.y, w1.x, accA.x); accA.y = fmaf(uA.y, w1.y, accA.y);
        accA.z = fmaf(uA.y, w1.z, accA.z); accA.w = fmaf(uA.y, w1.w, accA.w);
        accA.x = fmaf(uA.z, w2.x, accA.x); accA.y = fmaf(uA.z, w2.y, accA.y);
        accA.z = fmaf(uA.z, w2.z, accA.z); accA.w = fmaf(uA.z, w2.w, accA.w);
        accA.x = fmaf(uA.w, w3.x, accA.x); accA.y = fmaf(uA.w, w3.y, accA.y);
        accA.z = fmaf(uA.w, w3.z, accA.z); accA.w = fmaf(uA.w, w3.w, accA.w);
        accB.x = fmaf(uB.x, w0.x, accB.x); accB.y = fmaf(uB.x, w0.y, accB.y);
        accB.z = fmaf(uB.x, w0.z, accB.z); accB.w = fmaf(uB.x, w0.w, accB.w);
        accB.x = fmaf(uB.y, w1.x, accB.x); accB.y = fmaf(uB.y, w1.y, accB.y);
        accB.z = fmaf(uB.y, w1.z, accB.z); accB.w = fmaf(uB.y, w1.w, accB.w);
        accB.x = fmaf(uB.z, w2.x, accB.x); accB.y = fmaf(uB.z, w2.y, accB.y);
        accB.z = fmaf(uB.z, w2.z, accB.z); accB.w = fmaf(uB.z, w2.w, accB.w);
        accB.x = fmaf(uB.w, w3.x, accB.x); accB.y = fmaf(uB.w, w3.y, accB.y);
        accB.z = fmaf(uB.w, w3.z, accB.z); accB.w = fmaf(uB.w, w3.w, accB.w);
    }

    // tanh = 1 - 2/(e^2x + 1), then quarter-coalesced float4 stores
    float4 oA, oB;
    oA.x = 1.f - __fdividef(2.f, __expf(2.f * accA.x) + 1.f);
    oA.y = 1.f - __fdividef(2.f, __expf(2.f * accA.y) + 1.f);
    oA.z = 1.f - __fdividef(2.f, __expf(2.f * accA.z) + 1.f);
    oA.w = 1.f - __fdividef(2.f, __expf(2.f * accA.w) + 1.f);
    oB.x = 1.f - __fdividef(2.f, __expf(2.f * accB.x) + 1.f);
    oB.y = 1.f - __fdividef(2.f, __expf(2.f * accB.y) + 1.f);
    oB.z = 1.f - __fdividef(2.f, __expf(2.f * accB.z) + 1.f);
    oB.w = 1.f - __fdividef(2.f, __expf(2.f * accB.w) + 1.f);
    *(float4*)&out[(size_t)(r0 + w * 8 + rgrp) * 64 + colg * 4]     = oA;
    *(float4*)&out[(size_t)(r0 + w * 8 + 4 + rgrp) * 64 + colg * 4] = oB;
}

// ---------------------------------------------------------------------------
extern "C" void kernel_launch(void* const* d_in, const int* in_sizes, int n_in,
                              void* d_out, int out_size, void* d_ws, size_t ws_size,
                              hipStream_t stream)
{
    (void)in_sizes; (void)n_in; (void)out_size; (void)ws_size;
    const float* x  = (const float*)d_in[0];
    const float* Wf = (const float*)d_in[1];
    const float* bf = (const float*)d_in[2];
    const float* Ws = (const float*)d_in[3];
    const float* bs = (const float*)d_in[4];
    const float* Wo = (const float*)d_in[5];
    const float* bo = (const float*)d_in[6];
    float* out = (float*)d_out;

    float* coords = (float*)d_ws;                     // B*V*4  floats (256 KB)
    float* feats  = coords + (size_t)BB * VV * 4;     // B*V*64 floats (4 MB)
    float* mn     = feats + (size_t)BB * VV * 64;     // B*V*64 floats (4 MB)
    float* mx     = out;                              // d_out reused as scratch

    prep_kernel<<<BB * VV / 16, 256, 0, stream>>>(x, Wf, bf, Ws, bs,
                                                  coords, feats);
    gravnet_kernel<<<BB * VV / 4, 128, 0, stream>>>(coords, feats, mx, mn);
    out_gemm<<<BB * VV / 32, 256, 0, stream>>>(x, mx, mn, Wo, bo, out);
}

// Round 17
// 127.317 us; speedup vs baseline: 1.0612x; 1.0612x over previous
//
#include <hip/hip_runtime.h>
#include <cmath>

#define BB  4
#define VV  4096
#define KK  40
#define FIN 64

typedef float v2f __attribute__((ext_vector_type(2)));

// ---------------------------------------------------------------------------
// Kernel A: 16 rows/block (4 waves x 4 rows), coords + feats only (no sq).
// feats GEMM: lane = rgrp*16 + colg; each ds_read_b128 serves 4 different
// rows (64B payload); row stride 68 == 4 mod 32 -> conflict-free.
// ---------------------------------------------------------------------------
__global__ __launch_bounds__(256) void prep_kernel(
    const float* __restrict__ x, const float* __restrict__ Wf,
    const float* __restrict__ bf, const float* __restrict__ Ws,
    const float* __restrict__ bs,
    float* __restrict__ coords, float* __restrict__ feats)
{
    int tid  = threadIdx.x;
    int lane = tid & 63;
    int w    = tid >> 6;
    int row0 = blockIdx.x * 16 + w * 4;            // this wave's 4 rows

    __shared__ __align__(16) float sx[16 * 68];    // stride 68 = 4 mod 32

    #pragma unroll
    for (int i = 0; i < 4; ++i)                    // stage own rows, coalesced
        sx[(w * 4 + i) * 68 + lane] = x[(size_t)(row0 + i) * 64 + lane];
    // same-wave LDS write->read: compiler inserts waitcnt, no barrier

    int rgrp = lane >> 4;                          // row within quad
    int colg = lane & 15;                          // float4 column group
    const float4* Wf4 = (const float4*)Wf;
    float4 acc = make_float4(0.f, 0.f, 0.f, 0.f);
    #pragma unroll 4
    for (int k4 = 0; k4 < 16; ++k4) {
        float4 u  = *(const float4*)&sx[(w * 4 + rgrp) * 68 + k4 * 4];
        float4 w0 = Wf4[(k4 * 4 + 0) * 16 + colg];
        float4 w1 = Wf4[(k4 * 4 + 1) * 16 + colg];
        float4 w2 = Wf4[(k4 * 4 + 2) * 16 + colg];
        float4 w3 = Wf4[(k4 * 4 + 3) * 16 + colg];
        acc.x = fmaf(u.x, w0.x, acc.x); acc.y = fmaf(u.x, w0.y, acc.y);
        acc.z = fmaf(u.x, w0.z, acc.z); acc.w = fmaf(u.x, w0.w, acc.w);
        acc.x = fmaf(u.y, w1.x, acc.x); acc.y = fmaf(u.y, w1.y, acc.y);
        acc.z = fmaf(u.y, w1.z, acc.z); acc.w = fmaf(u.y, w1.w, acc.w);
        acc.x = fmaf(u.z, w2.x, acc.x); acc.y = fmaf(u.z, w2.y, acc.y);
        acc.z = fmaf(u.z, w2.z, acc.z); acc.w = fmaf(u.z, w2.w, acc.w);
        acc.x = fmaf(u.w, w3.x, acc.x); acc.y = fmaf(u.w, w3.y, acc.y);
        acc.z = fmaf(u.w, w3.z, acc.z); acc.w = fmaf(u.w, w3.w, acc.w);
    }
    float4 bf4 = ((const float4*)bf)[colg];
    acc.x += bf4.x; acc.y += bf4.y; acc.z += bf4.z; acc.w += bf4.w;
    *(float4*)&feats[(size_t)(row0 + rgrp) * 64 + colg * 4] = acc;

    // coords for the same 4 rows (per-lane global reads)
    int r  = lane >> 4;                            // 0..3 row
    int s  = (lane >> 2) & 3;                      // 0..3 coord dim
    int kc = lane & 3;                             // 0..3 k-chunk
    const float* xrr = x + (size_t)(row0 + r) * FIN + kc * 16;
    const float* wsr = Ws + kc * 16 * 4 + s;
    float c = 0.f;
    #pragma unroll
    for (int k = 0; k < 16; ++k)
        c = fmaf(xrr[k], wsr[k * 4], c);
    c += __shfl_xor(c, 1, 64);                     // reduce over kc
    c += __shfl_xor(c, 2, 64);
    float val = c + bs[s];
    if ((lane & 3) == 0) coords[(size_t)(row0 + r) * 4 + s] = val;
}

// ---------------------------------------------------------------------------
// Spill-proof helpers (rounds 9/10 lesson: no runtime-indexed locals).
// ---------------------------------------------------------------------------
__device__ __forceinline__ unsigned umed3(unsigned a, unsigned b, unsigned c)
{
    unsigned d;
    asm("v_med3_u32 %0, %1, %2, %3" : "=v"(d) : "v"(a), "v"(b), "v"(c));
    return d;
}

__device__ __forceinline__ int cnt_lt4(unsigned m0, unsigned m1,
                                       unsigned m2, unsigned m3,
                                       unsigned cand)
{
    return (int)__popcll(__ballot(m0 < cand))
         + (int)__popcll(__ballot(m1 < cand))
         + (int)__popcll(__ballot(m2 < cand))
         + (int)__popcll(__ballot(m3 < cand));
}

__device__ __forceinline__ unsigned select_thresh(unsigned m0, unsigned m1,
                                                  unsigned m2, unsigned m3)
{
    unsigned M = 0u;
    #pragma unroll
    for (int bit = 30; bit >= 12; --bit) {
        unsigned cand = M | (1u << bit);
        if (cnt_lt4(m0, m1, m2, m3, cand) <= 39) M = cand;
    }
    unsigned Msel = M | 0xFFFu;
    if (cnt_lt4(m0, m1, m2, m3, M + 4096u) != 40) {
        #pragma unroll
        for (int bit = 11; bit >= 0; --bit) {
            unsigned cand = M | (1u << bit);
            if (cnt_lt4(m0, m1, m2, m3, cand) <= 39) M = cand;
        }
        Msel = M;
    }
    return Msel;
}

__device__ __forceinline__ void compact4(unsigned m0, unsigned m1,
                                         unsigned m2, unsigned m3,
                                         unsigned Msel, uint2* dst)
{
    unsigned mn = m0;
    #pragma unroll
    for (int off = 32; off >= 1; off >>= 1) {
        unsigned o = __shfl_xor(mn, off, 64);
        mn = o < mn ? o : mn;
    }
    int base = 0;
    unsigned kk = m0;
    #pragma unroll
    for (int i = 0; i < 4; ++i) {
        bool pred = (kk <= Msel) && (kk != mn);
        unsigned long long mask = __ballot(pred);
        unsigned pos = (unsigned)base +
            __builtin_amdgcn_mbcnt_hi((unsigned)(mask >> 32),
                __builtin_amdgcn_mbcnt_lo((unsigned)mask, 0u));
        if (pred) {
            float d2a = __uint_as_float(kk & 0xFFFFF000u);
            float w   = __expf(-10.f * d2a);
            dst[pos] = make_uint2((kk & 4095u) << 8, __float_as_uint(w));
        }
        base += (int)__popcll(mask);
        kk = (i == 0) ? m1 : (i == 1) ? m2 : m3;   // static rotation
    }
}

// ---------------------------------------------------------------------------
// Kernel B (FUSED, round-12 skeleton — the best measured total): block =
// 4 waves = 8 queries (2 quads). Wave pair shares a quad; each wave runs
// distance+top-4 over HALF the candidates (32 iters, ONE VMEM stream —
// squ recomputed from cu, round-14 validated), publishes sorted quads,
// barrier, bitonic-partner merge (bit-identical), then each wave owns 2
// queries: 19-step radix select (+ rare exact fallback), compact with
// predecoded {off,w}, gather, and the fused pk_fma GEMV epilogue
// (interleaved float2 activations; Wo rows loaded once per wave).
// 3-kernel split (R14-16) was net-negative: out_gemm + extra launch +
// mx/mn HBM round-trip cost ~19 us vs ~8 us saved in gravnet.
// ---------------------------------------------------------------------------
__global__ __launch_bounds__(256) void gravnet_kernel(
    const float* __restrict__ x, const float* __restrict__ coords,
    const float* __restrict__ feats, const float* __restrict__ Wo,
    const float* __restrict__ bo, float* __restrict__ out)
{
    int lane = threadIdx.x & 63;
    int w    = threadIdx.x >> 6;              // wave 0..3
    int quad = w >> 1;                        // 0..1: which query-quad
    int half = w & 1;                         // which candidate half
    int qb   = blockIdx.x * 8 + quad * 4;     // quad's first global query
    int b    = (blockIdx.x * 8) >> 12;        // batch (uniform in block)
    int v0   = qb & (VV - 1);

    __shared__ __align__(16) char smem[16384];
    uint4* s_mrg  = (uint4*)smem;                      // [16][64] phase 1
    uint2* s_nb   = (uint2*)smem;                      // [8][KK]  phase 2
    v2f*   s_updp = (v2f*)(smem + 8 * KK * 8);         // [4][192] phase 2

    const float4* cb = (const float4*)(coords + (size_t)b * VV * 4);

    // quad query constants (lane-uniform); sqv from registers
    float4 cq0 = cb[v0],     cq1 = cb[v0 + 1];
    float4 cq2 = cb[v0 + 2], cq3 = cb[v0 + 3];
    float sv0 = fmaf(cq0.w, cq0.w, fmaf(cq0.z, cq0.z,
                fmaf(cq0.y, cq0.y, cq0.x * cq0.x)));
    float sv1 = fmaf(cq1.w, cq1.w, fmaf(cq1.z, cq1.z,
                fmaf(cq1.y, cq1.y, cq1.x * cq1.x)));
    float sv2 = fmaf(cq2.w, cq2.w, fmaf(cq2.z, cq2.z,
                fmaf(cq2.y, cq2.y, cq2.x * cq2.x)));
    float sv3 = fmaf(cq3.w, cq3.w, fmaf(cq3.z, cq3.z,
                fmaf(cq3.y, cq3.y, cq3.x * cq3.x)));
    v2f nxA = (v2f){-2.f * cq0.x, -2.f * cq1.x};
    v2f nyA = (v2f){-2.f * cq0.y, -2.f * cq1.y};
    v2f nzA = (v2f){-2.f * cq0.z, -2.f * cq1.z};
    v2f nwA = (v2f){-2.f * cq0.w, -2.f * cq1.w};
    v2f hsA = (v2f){sv0, sv1};
    v2f nxB = (v2f){-2.f * cq2.x, -2.f * cq3.x};
    v2f nyB = (v2f){-2.f * cq2.y, -2.f * cq3.y};
    v2f nzB = (v2f){-2.f * cq2.z, -2.f * cq3.z};
    v2f nwB = (v2f){-2.f * cq2.w, -2.f * cq3.w};
    v2f hsB = (v2f){sv2, sv3};
    v2f zero = (v2f){0.f, 0.f};

    // per-lane top-4 keys per quad-query, individually named (spill-proof)
    unsigned k00 = ~0u, k01 = ~0u, k02 = ~0u, k03 = ~0u;
    unsigned k10 = ~0u, k11 = ~0u, k12 = ~0u, k13 = ~0u;
    unsigned k20 = ~0u, k21 = ~0u, k22 = ~0u, k23 = ~0u;
    unsigned k30 = ~0u, k31 = ~0u, k32 = ~0u, k33 = ~0u;

    int i0 = half * 32;                        // this wave's candidate half
    #pragma unroll 4
    for (int i = i0; i < i0 + 32; ++i) {
        int u = i * 64 + lane;
        float4 cu = cb[u];                     // the only VMEM stream
        float squ = fmaf(cu.w, cu.w, fmaf(cu.z, cu.z,
                    fmaf(cu.y, cu.y, cu.x * cu.x)));
        v2f accA = hsA + (v2f){squ, squ};
        accA = __builtin_elementwise_fma(nxA, (v2f){cu.x, cu.x}, accA);
        accA = __builtin_elementwise_fma(nyA, (v2f){cu.y, cu.y}, accA);
        accA = __builtin_elementwise_fma(nzA, (v2f){cu.z, cu.z}, accA);
        accA = __builtin_elementwise_fma(nwA, (v2f){cu.w, cu.w}, accA);
        v2f accB = hsB + (v2f){squ, squ};
        accB = __builtin_elementwise_fma(nxB, (v2f){cu.x, cu.x}, accB);
        accB = __builtin_elementwise_fma(nyB, (v2f){cu.y, cu.y}, accB);
        accB = __builtin_elementwise_fma(nzB, (v2f){cu.z, cu.z}, accB);
        accB = __builtin_elementwise_fma(nwB, (v2f){cu.w, cu.w}, accB);
        accA = __builtin_elementwise_max(accA, zero);   // v_pk_max_f32
        accB = __builtin_elementwise_max(accB, zero);   // keys non-negative

        {   // q0: min + 3x med3, depth 1
            unsigned k = (__float_as_uint(accA.x) & 0xFFFFF000u) | (unsigned)u;
            unsigned n1 = umed3(k00, k01, k);
            unsigned n2 = umed3(k01, k02, k);
            unsigned n3 = umed3(k02, k03, k);
            k00 = min(k00, k); k01 = n1; k02 = n2; k03 = n3;
        }
        {   // q1
            unsigned k = (__float_as_uint(accA.y) & 0xFFFFF000u) | (unsigned)u;
            unsigned n1 = umed3(k10, k11, k);
            unsigned n2 = umed3(k11, k12, k);
            unsigned n3 = umed3(k12, k13, k);
            k10 = min(k10, k); k11 = n1; k12 = n2; k13 = n3;
        }
        {   // q2
            unsigned k = (__float_as_uint(accB.x) & 0xFFFFF000u) | (unsigned)u;
            unsigned n1 = umed3(k20, k21, k);
            unsigned n2 = umed3(k21, k22, k);
            unsigned n3 = umed3(k22, k23, k);
            k20 = min(k20, k); k21 = n1; k22 = n2; k23 = n3;
        }
        {   // q3
            unsigned k = (__float_as_uint(accB.y) & 0xFFFFF000u) | (unsigned)u;
            unsigned n1 = umed3(k30, k31, k);
            unsigned n2 = umed3(k31, k32, k);
            unsigned n3 = umed3(k32, k33, k);
            k30 = min(k30, k); k31 = n1; k32 = n2; k33 = n3;
        }
    }

    // --- publish sorted quads (one b128 per query)
    s_mrg[(w * 4 + 0) * 64 + lane] = make_uint4(k00, k01, k02, k03);
    s_mrg[(w * 4 + 1) * 64 + lane] = make_uint4(k10, k11, k12, k13);
    s_mrg[(w * 4 + 2) * 64 + lane] = make_uint4(k20, k21, k22, k23);
    s_mrg[(w * 4 + 3) * 64 + lane] = make_uint4(k30, k31, k32, k33);
    __syncthreads();

    // --- consume partner halves for this wave's 2 post-merge queries
    int p   = w ^ 1;
    int lq0 = half * 2;                        // local query within quad
    uint4 pb0 = s_mrg[(p * 4 + lq0)     * 64 + lane];
    uint4 pb1 = s_mrg[(p * 4 + lq0 + 1) * 64 + lane];
    unsigned oa0 = half ? k20 : k00, oa1 = half ? k21 : k01;
    unsigned oa2 = half ? k22 : k02, oa3 = half ? k23 : k03;
    unsigned ob0 = half ? k30 : k10, ob1 = half ? k31 : k11;
    unsigned ob2 = half ? k32 : k12, ob3 = half ? k33 : k13;
    __syncthreads();                           // before s_nb/s_updp reuse

    // --- bitonic-partner merge: lowest-4 of two sorted quads
    unsigned d0 = min(oa0, pb0.w), d1 = min(oa1, pb0.z);
    unsigned d2 = min(oa2, pb0.y), d3 = min(oa3, pb0.x);
    unsigned A0 = min(d0, d3), A3 = max(d0, d3);      // A0 = lane min
    unsigned e0 = min(ob0, pb1.w), e1 = min(ob1, pb1.z);
    unsigned e2 = min(ob2, pb1.y), e3 = min(ob3, pb1.x);
    unsigned B0 = min(e0, e3), B3 = max(e0, e3);

    // --- select + compact for the wave's 2 queries
    int s0 = w * 2, s1 = w * 2 + 1;            // LDS slots
    compact4(A0, d1, d2, A3, select_thresh(A0, d1, d2, A3), &s_nb[s0 * KK]);
    compact4(B0, e1, e2, B3, select_thresh(B0, e1, e2, B3), &s_nb[s1 * KK]);
    // s_nb reads below are same-wave: no barrier needed

    // --- gather 39 neighbours x 2 queries
    const float* fb  = feats + (size_t)b * VV * 64;
    const char*  fbl = (const char*)(fb + lane);
    float vmax0 = -INFINITY, vsum0 = 0.f, vmax1 = -INFINITY, vsum1 = 0.f;
    #pragma unroll 6
    for (int j = 0; j < KK - 1; ++j) {
        uint2 n0 = s_nb[s0 * KK + j];          // ds_read_b64 x2
        uint2 n1 = s_nb[s1 * KK + j];
        float f0 = *(const float*)(fbl + n0.x);
        float f1 = *(const float*)(fbl + n1.x);
        float g0 = __uint_as_float(n0.y) * f0;
        float g1 = __uint_as_float(n1.y) * f1;
        vmax0 = fmaxf(vmax0, g0); vsum0 += g0;
        vmax1 = fmaxf(vmax1, g1); vsum1 += g1;
    }

    // --- updated vectors to LDS, interleaved {q0,q1} float2 pairs
    int q0g = qb + lq0, q1g = qb + lq0 + 1;
    s_updp[w * 192 + lane]       = (v2f){x[(size_t)q0g * 64 + lane],
                                         x[(size_t)q1g * 64 + lane]};
    s_updp[w * 192 + 64  + lane] = (v2f){vmax0, vmax1};
    s_updp[w * 192 + 128 + lane] = (v2f){vsum0 * (1.0f / 39.0f),
                                         vsum1 * (1.0f / 39.0f)};

    // --- GEMV (192 x 64) x 2 via v_pk_fma_f32: Wo row loaded once
    float bol = bo[lane];
    v2f accp = (v2f){bol, bol};
    #pragma unroll 4
    for (int j4 = 0; j4 < 48; ++j4) {
        float wo0 = Wo[(j4 * 4 + 0) * 64 + lane];
        float wo1 = Wo[(j4 * 4 + 1) * 64 + lane];
        float wo2 = Wo[(j4 * 4 + 2) * 64 + lane];
        float wo3 = Wo[(j4 * 4 + 3) * 64 + lane];
        float4 r0 = *(const float4*)&s_updp[w * 192 + j4 * 4];     // pairs j,j+1
        float4 r1 = *(const float4*)&s_updp[w * 192 + j4 * 4 + 2]; // pairs j+2,j+3
        accp = __builtin_elementwise_fma((v2f){r0.x, r0.y}, (v2f){wo0, wo0}, accp);
        accp = __builtin_elementwise_fma((v2f){r0.z, r0.w}, (v2f){wo1, wo1}, accp);
        accp = __builtin_elementwise_fma((v2f){r1.x, r1.y}, (v2f){wo2, wo2}, accp);
        accp = __builtin_elementwise_fma((v2f){r1.z, r1.w}, (v2f){wo3, wo3}, accp);
    }
    float e0t = __expf(2.f * accp.x);          // tanh = 1 - 2/(e^2x+1)
    float e1t = __expf(2.f * accp.y);
    out[(size_t)q0g * 64 + lane] = 1.f - __fdividef(2.f, e0t + 1.f);
    out[(size_t)q1g * 64 + lane] = 1.f - __fdividef(2.f, e1t + 1.f);
}

// ---------------------------------------------------------------------------
extern "C" void kernel_launch(void* const* d_in, const int* in_sizes, int n_in,
                              void* d_out, int out_size, void* d_ws, size_t ws_size,
                              hipStream_t stream)
{
    (void)in_sizes; (void)n_in; (void)out_size; (void)ws_size;
    const float* x  = (const float*)d_in[0];
    const float* Wf = (const float*)d_in[1];
    const float* bf = (const float*)d_in[2];
    const float* Ws = (const float*)d_in[3];
    const float* bs = (const float*)d_in[4];
    const float* Wo = (const float*)d_in[5];
    const float* bo = (const float*)d_in[6];
    float* out = (float*)d_out;

    float* coords = (float*)d_ws;                     // B*V*4  floats (256 KB)
    float* feats  = coords + (size_t)BB * VV * 4;     // B*V*64 floats (4 MB)

    prep_kernel<<<BB * VV / 16, 256, 0, stream>>>(x, Wf, bf, Ws, bs,
                                                  coords, feats);
    gravnet_kernel<<<BB * VV / 8, 256, 0, stream>>>(x, coords, feats,
                                                    Wo, bo, out);
}